// Round 9
// baseline (346.172 us; speedup 1.0000x reference)
//
#include <hip/hip_runtime.h>

#define HH 8
#define LL 256
#define CC 32
#define VT_STRIDE 264   // padded sk2 stride for V^T, multiple of 8 (b128 align)
#define PC_STRIDE 40    // per-wave P chunk stride, multiple of 8 (b128 align)

typedef _Float16 f16x8 __attribute__((ext_vector_type(8)));
typedef _Float16 f16x4 __attribute__((ext_vector_type(4)));
typedef float    f32x4 __attribute__((ext_vector_type(4)));

// Transpose bias (B=1, s2, sk2, H) -> biasT [H][s2][sk2] so the main kernel's
// bias loads become lane-coalesced float4.
__global__ __launch_bounds__(256)
void bias_transpose(const float* __restrict__ bias, float* __restrict__ biasT) {
    const int g = blockIdx.x * 256 + threadIdx.x;   // g = h*65536 + s2*256 + sk2
    const int h = g >> 16;
    const int s2sk2 = g & 65535;
    biasT[g] = bias[(s2sk2 << 3) | h];
}

// Flash-split over sk2 (two 128-wide halves, online softmax).
// R8 fixed the store scatter (WRITE 307->91, FETCH 842->351, dur 334->150us).
// This round: pure-latency changes on the verified structure -- bias half-0
// prefetched at strip top (hides under QK^T MFMAs), half-1 issued when half-0
// dies (hides under softmax+PV0); gate prefetched at strip top. No traffic
// change expected: this isolates latency- vs BW-bound for the remaining gap
// (dur 150 vs ~105us traffic floor; all pipes <40%).
__global__ __launch_bounds__(256, 4)
void triattn(const float* __restrict__ q, const float* __restrict__ k,
             const float* __restrict__ v, const float* __restrict__ bias,
             const float* __restrict__ biasT,   // may be null -> fallback path
             const float* __restrict__ gate, float* __restrict__ out) {
    __shared__ _Float16 Klds[LL * CC];            // [sk2][32]      16384 B
    __shared__ _Float16 Vt[CC * VT_STRIDE];       // [c][sk2]       16896 B
    __shared__ _Float16 Pc[4][16 * PC_STRIDE];    // per-wave chunk  5120 B
                                                  // (reused as 1KB f32 out-stage)

    const int h    = blockIdx.y;
    const int s1   = blockIdx.x;
    const int tid  = threadIdx.x;
    const int wave = tid >> 6;
    const int lane = tid & 63;
    const int n16  = lane & 15;
    const int quad = lane >> 4;

    const size_t base = ((size_t)(h * LL + s1)) * (LL * CC);
    const float* qb = q + base;
    const float* kb = k + base;
    const float* vb = v + base;
    float*       ob = out + base;
    const float* gateb = gate + ((size_t)s1 * (LL * CC * HH)) + h;

    // ---- issue strip-0 Q fragment loads early (hidden under K/V staging) ----
    f32x4 qA, qB;
    {
        const f32x4* qr4 = (const f32x4*)(qb + (size_t)(wave * 64 + n16) * CC + quad * 8);
        qA = __builtin_nontemporal_load(qr4);
        qB = __builtin_nontemporal_load(qr4 + 1);
    }

    // ---- stage K and V^T into LDS as fp16 (NT loads: stream-once, read-only) ----
    const f32x4* k4 = (const f32x4*)kb;
    const f32x4* v4 = (const f32x4*)vb;
    #pragma unroll
    for (int i = 0; i < 8; ++i) {
        const int idx = tid + i * 256;        // f32x4 index over 2048
        const int row = idx >> 3;             // sk2
        const int c0  = (idx & 7) * 4;        // channel base
        f32x4 f = __builtin_nontemporal_load(k4 + idx);
        f16x4 kv4 = { (_Float16)f[0], (_Float16)f[1], (_Float16)f[2], (_Float16)f[3] };
        *(f16x4*)&Klds[row * CC + c0] = kv4;
        f32x4 g = __builtin_nontemporal_load(v4 + idx);
        _Float16* vd = &Vt[c0 * VT_STRIDE + row];
        vd[0]             = (_Float16)g[0];
        vd[VT_STRIDE]     = (_Float16)g[1];
        vd[2 * VT_STRIDE] = (_Float16)g[2];
        vd[3 * VT_STRIDE] = (_Float16)g[3];
    }
    __syncthreads();

    _Float16* pw = Pc[wave];
    float*    ow = (float*)pw;                // per-wave 1KB f32 out-stage

    #pragma unroll 1
    for (int si = 0; si < 4; ++si) {
        const int strip = wave * 4 + si;
        const int r0 = strip * 16;            // s2 base for this strip

        // Q as B-operand fragment: B[k=c=quad*8+j][n=s2=n16]
        f16x8 qf;
        qf[0] = (_Float16)qA[0]; qf[1] = (_Float16)qA[1];
        qf[2] = (_Float16)qA[2]; qf[3] = (_Float16)qA[3];
        qf[4] = (_Float16)qB[0]; qf[5] = (_Float16)qB[1];
        qf[6] = (_Float16)qB[2]; qf[7] = (_Float16)qB[3];

        // prefetch next strip's Q (consumed at next iteration's top)
        if (si < 3) {
            const f32x4* qr4 = (const f32x4*)(qb + (size_t)(r0 + 16 + n16) * CC + quad * 8);
            qA = __builtin_nontemporal_load(qr4);
            qB = __builtin_nontemporal_load(qr4 + 1);
        }

        // ---- gate prefetch (consumed in epilogue, far away) ----
        float gp0[4], gp1[4];
        #pragma unroll
        for (int r = 0; r < 4; ++r) {
            const int s2g = r0 + quad * 4 + r;
            gp0[r] = gateb[(s2g * CC + n16) * HH];
            gp1[r] = gateb[(s2g * CC + 16 + n16) * HH];
        }

        // ---- bias half-0 prefetch (consumed after the QK^T MFMAs) ----
        const f32x4* bb = biasT
            ? (const f32x4*)(biasT + ((size_t)h << 16) + (size_t)(r0 + n16) * LL) + quad
            : nullptr;
        const float* bb2 = bias + h + ((size_t)(r0 + n16) * LL + quad * 4) * HH;
        f32x4 bv[8];
        if (bb) {
            #pragma unroll
            for (int t = 0; t < 8; ++t) bv[t] = bb[t * 4];
        } else {
            #pragma unroll
            for (int t = 0; t < 8; ++t)
                #pragma unroll
                for (int r = 0; r < 4; ++r) bv[t][r] = bb2[(t * 16 + r) * HH];
        }

        f32x4 o0 = {0.f, 0.f, 0.f, 0.f}, o1 = {0.f, 0.f, 0.f, 0.f};
        float mrow = 0.f;   // valid after hh=0
        float srow = 0.f;

        #pragma unroll
        for (int hh = 0; hh < 2; ++hh) {
            // ---- S^T half: acc[t] row = sk2 = (hh*8+t)*16+quad*4+r, col = s2 = n16 ----
            f32x4 acc[8];
            #pragma unroll
            for (int t = 0; t < 8; ++t) {
                f16x8 kf = *(const f16x8*)&Klds[((hh * 8 + t) * 16 + n16) * CC + quad * 8];
                f32x4 z = {0.f, 0.f, 0.f, 0.f};
                acc[t] = __builtin_amdgcn_mfma_f32_16x16x32_f16(kf, qf, z, 0, 0, 0);
            }

            // ---- bias add from prefetched regs ----
            #pragma unroll
            for (int t = 0; t < 8; ++t) {
                acc[t][0] += bv[t][0]; acc[t][1] += bv[t][1];
                acc[t][2] += bv[t][2]; acc[t][3] += bv[t][3];
            }

            // ---- bias half-1 issue NOW (bv dead): hides under softmax+PV0 ----
            if (hh == 0) {
                if (bb) {
                    #pragma unroll
                    for (int t = 0; t < 8; ++t) bv[t] = bb[(8 + t) * 4];
                } else {
                    #pragma unroll
                    for (int t = 0; t < 8; ++t)
                        #pragma unroll
                        for (int r = 0; r < 4; ++r) bv[t][r] = bb2[((8 + t) * 16 + r) * HH];
                }
            }

            // ---- local row-max (rows = s2 = n16; quad-uniform after shuffles) ----
            f32x4 mv = acc[0];
            #pragma unroll
            for (int t = 1; t < 8; ++t) {
                mv[0] = fmaxf(mv[0], acc[t][0]); mv[1] = fmaxf(mv[1], acc[t][1]);
                mv[2] = fmaxf(mv[2], acc[t][2]); mv[3] = fmaxf(mv[3], acc[t][3]);
            }
            float ml = fmaxf(fmaxf(mv[0], mv[1]), fmaxf(mv[2], mv[3]));
            ml = fmaxf(ml, __shfl_xor(ml, 16));
            ml = fmaxf(ml, __shfl_xor(ml, 32));

            const float mNew = (hh == 0) ? ml : fmaxf(mrow, ml);

            // ---- exp + local sum ----
            f32x4 sv = {0.f, 0.f, 0.f, 0.f};
            #pragma unroll
            for (int t = 0; t < 8; ++t) {
                #pragma unroll
                for (int r = 0; r < 4; ++r) {
                    float p = exp2f((acc[t][r] - mNew) * 1.44269504f);
                    acc[t][r] = p;
                    sv[r] += p;
                }
            }
            float sl = (sv[0] + sv[1]) + (sv[2] + sv[3]);
            sl += __shfl_xor(sl, 16);
            sl += __shfl_xor(sl, 32);

            if (hh == 0) {
                srow = sl;
            } else {
                const float alpha = exp2f((mrow - mNew) * 1.44269504f);
                srow = srow * alpha + sl;
                // rescale o BEFORE accumulating this half's PV
                #pragma unroll
                for (int r = 0; r < 4; ++r) {
                    const float ar = __shfl(alpha, quad * 4 + r);
                    o0[r] *= ar; o1[r] *= ar;
                }
            }
            mrow = mNew;

            // ---- PV for this half: kk chunks of 32 sk2 ----
            #pragma unroll
            for (int kl = 0; kl < 4; ++kl) {
                const int kg = hh * 4 + kl;
                const int t0 = 2 * kl, t1 = 2 * kl + 1;
                f16x4 pa = { (_Float16)acc[t0][0], (_Float16)acc[t0][1],
                             (_Float16)acc[t0][2], (_Float16)acc[t0][3] };
                f16x4 pb = { (_Float16)acc[t1][0], (_Float16)acc[t1][1],
                             (_Float16)acc[t1][2], (_Float16)acc[t1][3] };
                *(f16x4*)&pw[n16 * PC_STRIDE + quad * 4]      = pa;
                *(f16x4*)&pw[n16 * PC_STRIDE + 16 + quad * 4] = pb;
                // same-wave DS ops are in-order: read sees this chunk's data,
                // and the next chunk's overwrite cannot pass this read.
                f16x8 pf  = *(const f16x8*)&pw[n16 * PC_STRIDE + quad * 8];
                f16x8 vf0 = *(const f16x8*)&Vt[n16 * VT_STRIDE + kg * 32 + quad * 8];
                f16x8 vf1 = *(const f16x8*)&Vt[(16 + n16) * VT_STRIDE + kg * 32 + quad * 8];
                o0 = __builtin_amdgcn_mfma_f32_16x16x32_f16(pf, vf0, o0, 0, 0, 0);
                o1 = __builtin_amdgcn_mfma_f32_16x16x32_f16(pf, vf1, o1, 0, 0, 0);
            }
        }

        // ---- epilogue: normalize + gate (prefetched) in registers ----
        const float inv = 1.f / srow;   // per s2-row (indexed by n16)
        float v0[4], v1[4];
        #pragma unroll
        for (int r = 0; r < 4; ++r) {
            const float wr = __shfl(inv, quad * 4 + r);
            v0[r] = o0[r] * wr * gp0[r];
            v1[r] = o1[r] * wr * gp1[r];
        }

        // ---- stage 16x32 f32 through per-wave LDS in two 1KB rounds, then
        // store fully-contiguous line-aligned 1KB bursts (R8: WRITE 307->91,
        // FETCH 842->351). asm fences pin the f16/f32 LDS type-pun ordering;
        // same-wave DS is HW-in-order. ----
        #pragma unroll
        for (int g = 0; g < 2; ++g) {
            asm volatile("" ::: "memory");
            if ((quad >> 1) == g) {           // quads 2g..2g+1 own rows 8g..8g+7
                const int bq = quad & 1;
                #pragma unroll
                for (int r = 0; r < 4; ++r) {
                    ow[(bq * 4 + r) * 32 + n16]      = v0[r];
                    ow[(bq * 4 + r) * 32 + 16 + n16] = v1[r];
                }
            }
            asm volatile("" ::: "memory");
            f32x4 sv4 = *(const f32x4*)&ow[lane * 4];
            asm volatile("" ::: "memory");
            *((f32x4*)(ob + (size_t)(r0 + g * 8) * CC) + lane) = sv4;
        }
    }
}

extern "C" void kernel_launch(void* const* d_in, const int* in_sizes, int n_in,
                              void* d_out, int out_size, void* d_ws, size_t ws_size,
                              hipStream_t stream) {
    const float* q    = (const float*)d_in[0];
    const float* k    = (const float*)d_in[1];
    const float* v    = (const float*)d_in[2];
    const float* bias = (const float*)d_in[3];
    const float* gate = (const float*)d_in[4];
    float* out = (float*)d_out;

    float* biasT = nullptr;
    if (ws_size >= (size_t)HH * LL * LL * sizeof(float)) {
        biasT = (float*)d_ws;
        bias_transpose<<<dim3((HH * LL * LL) / 256), 256, 0, stream>>>(bias, biasT);
    }
    dim3 grid(LL, HH);
    triattn<<<grid, 256, 0, stream>>>(q, k, v, bias, biasT, gate, out);
}

// Round 10
// 320.588 us; speedup vs baseline: 1.0798x; 1.0798x over previous
//
#include <hip/hip_runtime.h>

#define HH 8
#define LL 256
#define CC 32
#define NW 8            // waves per block (512 threads): LDS amortized over 2x waves
#define VT_STRIDE 264   // padded sk2 stride for V^T, multiple of 8 (b128 align)
#define PC_STRIDE 40    // per-wave P chunk stride, multiple of 8 (b128 align)

typedef _Float16 f16x8 __attribute__((ext_vector_type(8)));
typedef _Float16 f16x4 __attribute__((ext_vector_type(4)));
typedef float    f32x4 __attribute__((ext_vector_type(4)));

// Transpose bias (B=1, s2, sk2, H) -> biasT [H][s2][sk2] so the main kernel's
// bias loads become lane-coalesced float4.
__global__ __launch_bounds__(256)
void bias_transpose(const float* __restrict__ bias, float* __restrict__ biasT) {
    const int g = blockIdx.x * 256 + threadIdx.x;   // g = h*65536 + s2*256 + sk2
    const int h = g >> 16;
    const int s2sk2 = g & 65535;
    biasT[g] = bias[(s2sk2 << 3) | h];
}

// Flash-split over sk2 (two 128-wide halves, online softmax), R8-verified body.
// R9 lesson: register prefetch spilled (traffic +91MB) -> reverted; compiler
// already schedules loads well at 64 regs. This round's single change:
// 512-thread blocks (8 waves, 2 strips/wave). K/V LDS is per-(h,s1), so
// bigger blocks amortize it: 43.5KB/block -> 3 blocks/CU x 8 waves = 24/32
// waves (75% occupancy cap) vs R8's 4x4 = 16/32 (50%). Pure TLP increase,
// zero traffic / register change -- isolates the latency-bound hypothesis.
__global__ __launch_bounds__(512, 4)
void triattn(const float* __restrict__ q, const float* __restrict__ k,
             const float* __restrict__ v, const float* __restrict__ bias,
             const float* __restrict__ biasT,   // may be null -> fallback path
             const float* __restrict__ gate, float* __restrict__ out) {
    __shared__ _Float16 Klds[LL * CC];            // [sk2][32]      16384 B
    __shared__ _Float16 Vt[CC * VT_STRIDE];       // [c][sk2]       16896 B
    __shared__ _Float16 Pc[NW][16 * PC_STRIDE];   // per-wave chunk 10240 B
                                                  // (reused as 1KB f32 out-stage)

    const int h    = blockIdx.y;
    const int s1   = blockIdx.x;
    const int tid  = threadIdx.x;
    const int wave = tid >> 6;
    const int lane = tid & 63;
    const int n16  = lane & 15;
    const int quad = lane >> 4;

    const size_t base = ((size_t)(h * LL + s1)) * (LL * CC);
    const float* qb = q + base;
    const float* kb = k + base;
    const float* vb = v + base;
    float*       ob = out + base;
    const float* gateb = gate + ((size_t)s1 * (LL * CC * HH)) + h;

    // ---- issue strip-0 Q fragment loads early (hidden under K/V staging) ----
    f32x4 qA, qB;
    {
        const f32x4* qr4 = (const f32x4*)(qb + (size_t)(wave * 32 + n16) * CC + quad * 8);
        qA = __builtin_nontemporal_load(qr4);
        qB = __builtin_nontemporal_load(qr4 + 1);
    }

    // ---- stage K and V^T into LDS as fp16 (NT loads: stream-once, read-only) ----
    const f32x4* k4 = (const f32x4*)kb;
    const f32x4* v4 = (const f32x4*)vb;
    #pragma unroll
    for (int i = 0; i < 4; ++i) {
        const int idx = tid + i * 512;        // f32x4 index over 2048
        const int row = idx >> 3;             // sk2
        const int c0  = (idx & 7) * 4;        // channel base
        f32x4 f = __builtin_nontemporal_load(k4 + idx);
        f16x4 kv4 = { (_Float16)f[0], (_Float16)f[1], (_Float16)f[2], (_Float16)f[3] };
        *(f16x4*)&Klds[row * CC + c0] = kv4;
        f32x4 g = __builtin_nontemporal_load(v4 + idx);
        _Float16* vd = &Vt[c0 * VT_STRIDE + row];
        vd[0]             = (_Float16)g[0];
        vd[VT_STRIDE]     = (_Float16)g[1];
        vd[2 * VT_STRIDE] = (_Float16)g[2];
        vd[3 * VT_STRIDE] = (_Float16)g[3];
    }
    __syncthreads();

    _Float16* pw = Pc[wave];
    float*    ow = (float*)pw;                // per-wave 1KB f32 out-stage

    #pragma unroll 1
    for (int si = 0; si < 2; ++si) {
        const int strip = wave * 2 + si;
        const int r0 = strip * 16;            // s2 base for this strip

        // Q as B-operand fragment: B[k=c=quad*8+j][n=s2=n16]
        f16x8 qf;
        qf[0] = (_Float16)qA[0]; qf[1] = (_Float16)qA[1];
        qf[2] = (_Float16)qA[2]; qf[3] = (_Float16)qA[3];
        qf[4] = (_Float16)qB[0]; qf[5] = (_Float16)qB[1];
        qf[6] = (_Float16)qB[2]; qf[7] = (_Float16)qB[3];

        // prefetch next strip's Q (consumed at next iteration's top)
        if (si < 1) {
            const f32x4* qr4 = (const f32x4*)(qb + (size_t)(r0 + 16 + n16) * CC + quad * 8);
            qA = __builtin_nontemporal_load(qr4);
            qB = __builtin_nontemporal_load(qr4 + 1);
        }

        f32x4 o0 = {0.f, 0.f, 0.f, 0.f}, o1 = {0.f, 0.f, 0.f, 0.f};
        float mrow = 0.f;   // valid after hh=0
        float srow = 0.f;

        #pragma unroll
        for (int hh = 0; hh < 2; ++hh) {
            // ---- S^T half: acc[t] row = sk2 = (hh*8+t)*16+quad*4+r, col = s2 = n16 ----
            f32x4 acc[8];
            #pragma unroll
            for (int t = 0; t < 8; ++t) {
                f16x8 kf = *(const f16x8*)&Klds[((hh * 8 + t) * 16 + n16) * CC + quad * 8];
                f32x4 z = {0.f, 0.f, 0.f, 0.f};
                acc[t] = __builtin_amdgcn_mfma_f32_16x16x32_f16(kf, qf, z, 0, 0, 0);
            }

            // ---- bias add: bias[s2 = r0+n16][sk2 = (hh*8+t)*16+quad*4+r] ----
            if (biasT) {
                const f32x4* bb = (const f32x4*)(biasT + ((size_t)h << 16)
                                                 + (size_t)(r0 + n16) * LL) + quad;
                #pragma unroll
                for (int t = 0; t < 8; ++t) {
                    f32x4 bv = bb[(hh * 8 + t) * 4];
                    acc[t][0] += bv[0]; acc[t][1] += bv[1];
                    acc[t][2] += bv[2]; acc[t][3] += bv[3];
                }
            } else {
                const float* bb2 = bias + h + ((size_t)(r0 + n16) * LL + quad * 4) * HH;
                #pragma unroll
                for (int t = 0; t < 8; ++t)
                    #pragma unroll
                    for (int r = 0; r < 4; ++r)
                        acc[t][r] += bb2[((hh * 8 + t) * 16 + r) * HH];
            }

            // ---- local row-max (rows = s2 = n16; quad-uniform after shuffles) ----
            f32x4 mv = acc[0];
            #pragma unroll
            for (int t = 1; t < 8; ++t) {
                mv[0] = fmaxf(mv[0], acc[t][0]); mv[1] = fmaxf(mv[1], acc[t][1]);
                mv[2] = fmaxf(mv[2], acc[t][2]); mv[3] = fmaxf(mv[3], acc[t][3]);
            }
            float ml = fmaxf(fmaxf(mv[0], mv[1]), fmaxf(mv[2], mv[3]));
            ml = fmaxf(ml, __shfl_xor(ml, 16));
            ml = fmaxf(ml, __shfl_xor(ml, 32));

            const float mNew = (hh == 0) ? ml : fmaxf(mrow, ml);

            // ---- exp + local sum ----
            f32x4 sv = {0.f, 0.f, 0.f, 0.f};
            #pragma unroll
            for (int t = 0; t < 8; ++t) {
                #pragma unroll
                for (int r = 0; r < 4; ++r) {
                    float p = exp2f((acc[t][r] - mNew) * 1.44269504f);
                    acc[t][r] = p;
                    sv[r] += p;
                }
            }
            float sl = (sv[0] + sv[1]) + (sv[2] + sv[3]);
            sl += __shfl_xor(sl, 16);
            sl += __shfl_xor(sl, 32);

            if (hh == 0) {
                srow = sl;
            } else {
                const float alpha = exp2f((mrow - mNew) * 1.44269504f);
                srow = srow * alpha + sl;
                // rescale o BEFORE accumulating this half's PV
                #pragma unroll
                for (int r = 0; r < 4; ++r) {
                    const float ar = __shfl(alpha, quad * 4 + r);
                    o0[r] *= ar; o1[r] *= ar;
                }
            }
            mrow = mNew;

            // ---- PV for this half: kk chunks of 32 sk2 ----
            #pragma unroll
            for (int kl = 0; kl < 4; ++kl) {
                const int kg = hh * 4 + kl;
                const int t0 = 2 * kl, t1 = 2 * kl + 1;
                f16x4 pa = { (_Float16)acc[t0][0], (_Float16)acc[t0][1],
                             (_Float16)acc[t0][2], (_Float16)acc[t0][3] };
                f16x4 pb = { (_Float16)acc[t1][0], (_Float16)acc[t1][1],
                             (_Float16)acc[t1][2], (_Float16)acc[t1][3] };
                *(f16x4*)&pw[n16 * PC_STRIDE + quad * 4]      = pa;
                *(f16x4*)&pw[n16 * PC_STRIDE + 16 + quad * 4] = pb;
                // same-wave DS ops are in-order: read sees this chunk's data,
                // and the next chunk's overwrite cannot pass this read.
                f16x8 pf  = *(const f16x8*)&pw[n16 * PC_STRIDE + quad * 8];
                f16x8 vf0 = *(const f16x8*)&Vt[n16 * VT_STRIDE + kg * 32 + quad * 8];
                f16x8 vf1 = *(const f16x8*)&Vt[(16 + n16) * VT_STRIDE + kg * 32 + quad * 8];
                o0 = __builtin_amdgcn_mfma_f32_16x16x32_f16(pf, vf0, o0, 0, 0, 0);
                o1 = __builtin_amdgcn_mfma_f32_16x16x32_f16(pf, vf1, o1, 0, 0, 0);
            }
        }

        // ---- epilogue: normalize + gate in compute layout (registers) ----
        const float inv = 1.f / srow;   // per s2-row (indexed by n16)
        float v0[4], v1[4];
        #pragma unroll
        for (int r = 0; r < 4; ++r) {
            const float wr = __shfl(inv, quad * 4 + r);
            const int s2 = r0 + quad * 4 + r;
            // raw gate, plain loads: lines shared by all 8 h-blocks via L2
            const float g0 = gateb[(s2 * CC + n16) * HH];
            const float g1 = gateb[(s2 * CC + 16 + n16) * HH];
            v0[r] = o0[r] * wr * g0;
            v1[r] = o1[r] * wr * g1;
        }

        // ---- stage 16x32 f32 through per-wave LDS in two 1KB rounds, then
        // store fully-contiguous line-aligned 1KB bursts (R8: WRITE 307->91,
        // FETCH 842->351). asm fences pin the f16/f32 LDS type-pun ordering;
        // same-wave DS is HW-in-order. ----
        #pragma unroll
        for (int g = 0; g < 2; ++g) {
            asm volatile("" ::: "memory");
            if ((quad >> 1) == g) {           // quads 2g..2g+1 own rows 8g..8g+7
                const int bq = quad & 1;
                #pragma unroll
                for (int r = 0; r < 4; ++r) {
                    ow[(bq * 4 + r) * 32 + n16]      = v0[r];
                    ow[(bq * 4 + r) * 32 + 16 + n16] = v1[r];
                }
            }
            asm volatile("" ::: "memory");
            f32x4 sv4 = *(const f32x4*)&ow[lane * 4];
            asm volatile("" ::: "memory");
            *((f32x4*)(ob + (size_t)(r0 + g * 8) * CC) + lane) = sv4;
        }
    }
}

extern "C" void kernel_launch(void* const* d_in, const int* in_sizes, int n_in,
                              void* d_out, int out_size, void* d_ws, size_t ws_size,
                              hipStream_t stream) {
    const float* q    = (const float*)d_in[0];
    const float* k    = (const float*)d_in[1];
    const float* v    = (const float*)d_in[2];
    const float* bias = (const float*)d_in[3];
    const float* gate = (const float*)d_in[4];
    float* out = (float*)d_out;

    float* biasT = nullptr;
    if (ws_size >= (size_t)HH * LL * LL * sizeof(float)) {
        biasT = (float*)d_ws;
        bias_transpose<<<dim3((HH * LL * LL) / 256), 256, 0, stream>>>(bias, biasT);
    }
    dim3 grid(LL, HH);
    triattn<<<grid, 512, 0, stream>>>(q, k, v, bias, biasT, gate, out);
}